// Round 2
// baseline (224.125 us; speedup 1.0000x reference)
//
#include <hip/hip_runtime.h>

// ---------------------------------------------------------------------------
// RMSNormSparse: out = weight * (mask?x:0) * rsqrt(mean((mask?x:0)^2) + eps)
// B=4, S=4096, D=4096, fp32 in/out. Memory-bound streaming kernel.
//
// Round-2 structure: WAVE-PER-ROW (64 lanes x 64 floats = 4096). No
// __syncthreads, no LDS reduce -- each wave is fully independent, keeping
// ~20 vector loads in flight per wave with no barrier drain. Reduce is 6x
// __shfl_xor. Output stores are non-temporal (write-once; preserve L3 for
// x + mask -- rocprof showed the uint8 mask is fully L3-resident).
//
// Mask layout detection (flag in d_ws): 0 = uint8, 1 = int32, 2 = float32.
// Round-1 FETCH_SIZE (~= x only) confirms uint8; flags 1/2 keep a
// low-register two-pass fallback so they don't inflate the fast path's
// VGPR allocation.
// ---------------------------------------------------------------------------

#define EPS_RMS 1e-5f

typedef float f32x4 __attribute__((ext_vector_type(4)));

__global__ void detect_mask_kernel(const unsigned char* __restrict__ mb,
                                   int* __restrict__ flag) {
    __shared__ int nz_off;  // any nonzero byte at offset%4 != 0
    __shared__ int f3;      // any 0x3f byte at offset%4 == 3  -> float32
    if (threadIdx.x == 0) { nz_off = 0; f3 = 0; }
    __syncthreads();
    unsigned int i = threadIdx.x * 4u;  // 256 threads x 4 bytes = 1024 bytes
    unsigned char b1 = mb[i + 1], b2 = mb[i + 2], b3 = mb[i + 3];
    if ((b1 | b2 | b3) != 0) atomicOr(&nz_off, 1);
    if (b3 == 0x3fu) atomicOr(&f3, 1);
    __syncthreads();
    if (threadIdx.x == 0) {
        *flag = f3 ? 2 : (nz_off ? 0 : 1);
    }
}

// Fast path: D == 4096. One wave per row, 4 rows per 256-thread block.
__global__ __launch_bounds__(256) void rmsnorm_sparse_wave4096(
    const float* __restrict__ x,
    const void* __restrict__ mask,
    const float* __restrict__ weight,
    float* __restrict__ out,
    const int* __restrict__ flag_p,
    int nrows) {
    const int lane = threadIdx.x & 63;
    const int row = blockIdx.x * 4 + (threadIdx.x >> 6);
    if (row >= nrows) return;

    const int flag = *flag_p;  // uniform scalar load; gates only mask loads
    const size_t base = (size_t)row * 4096u;
    const f32x4* __restrict__ x4 = (const f32x4*)(x + base);
    const f32x4* __restrict__ w4 = (const f32x4*)weight;
    f32x4* __restrict__ o4 = (f32x4*)(out + base);

    if (flag == 0) {
        // ---- fast path: uint8 mask, everything register-resident ----
        const uchar4* __restrict__ m4 =
            (const uchar4*)((const unsigned char*)mask + base);
        f32x4 v[16];
#pragma unroll
        for (int w = 0; w < 16; ++w) v[w] = x4[lane + 64 * w];
        uchar4 mm[16];
#pragma unroll
        for (int w = 0; w < 16; ++w) mm[w] = m4[lane + 64 * w];

        float s = 0.f;
#pragma unroll
        for (int w = 0; w < 16; ++w) {
            f32x4 xv = v[w];
            const uchar4 u = mm[w];
            xv.x = u.x ? xv.x : 0.f;
            xv.y = u.y ? xv.y : 0.f;
            xv.z = u.z ? xv.z : 0.f;
            xv.w = u.w ? xv.w : 0.f;
            v[w] = xv;
            s += xv.x * xv.x + xv.y * xv.y + xv.z * xv.z + xv.w * xv.w;
        }
#pragma unroll
        for (int off = 1; off < 64; off <<= 1) s += __shfl_xor(s, off);
        const float scale = rsqrtf(s * (1.0f / 4096.0f) + EPS_RMS);

#pragma unroll
        for (int w = 0; w < 16; ++w) {
            const f32x4 wv = w4[lane + 64 * w];
            const f32x4 o = v[w] * (scale)*wv;
            __builtin_nontemporal_store(o, &o4[lane + 64 * w]);
        }
    } else {
        // ---- rare path: int32/float32 mask, low-register two-pass ----
        float s = 0.f;
        if (flag == 1) {
            const int4* m4 = (const int4*)((const int*)mask + base);
            for (int w = 0; w < 16; ++w) {
                const f32x4 xv = x4[lane + 64 * w];
                const int4 u = m4[lane + 64 * w];
                s += (u.x ? xv.x * xv.x : 0.f) + (u.y ? xv.y * xv.y : 0.f) +
                     (u.z ? xv.z * xv.z : 0.f) + (u.w ? xv.w * xv.w : 0.f);
            }
        } else {
            const f32x4* m4 = (const f32x4*)((const float*)mask + base);
            for (int w = 0; w < 16; ++w) {
                const f32x4 xv = x4[lane + 64 * w];
                const f32x4 u = m4[lane + 64 * w];
                s += (u.x != 0.f ? xv.x * xv.x : 0.f) +
                     (u.y != 0.f ? xv.y * xv.y : 0.f) +
                     (u.z != 0.f ? xv.z * xv.z : 0.f) +
                     (u.w != 0.f ? xv.w * xv.w : 0.f);
            }
        }
#pragma unroll
        for (int off = 1; off < 64; off <<= 1) s += __shfl_xor(s, off);
        const float scale = rsqrtf(s * (1.0f / 4096.0f) + EPS_RMS);

        for (int w = 0; w < 16; ++w) {
            f32x4 xv = x4[lane + 64 * w];  // re-read: L2-hot, row just fetched
            if (flag == 1) {
                const int4 u = ((const int4*)((const int*)mask + base))[lane + 64 * w];
                xv.x = u.x ? xv.x : 0.f;
                xv.y = u.y ? xv.y : 0.f;
                xv.z = u.z ? xv.z : 0.f;
                xv.w = u.w ? xv.w : 0.f;
            } else {
                const f32x4 u =
                    ((const f32x4*)((const float*)mask + base))[lane + 64 * w];
                xv.x = (u.x != 0.f) ? xv.x : 0.f;
                xv.y = (u.y != 0.f) ? xv.y : 0.f;
                xv.z = (u.z != 0.f) ? xv.z : 0.f;
                xv.w = (u.w != 0.f) ? xv.w : 0.f;
            }
            const f32x4 wv = w4[lane + 64 * w];
            o4[lane + 64 * w] = xv * scale * wv;
        }
    }
}

// Generic fallback for D != 4096 (scalar, two-phase; correctness only).
__global__ void rmsnorm_sparse_generic(const float* __restrict__ x,
                                       const void* __restrict__ mask,
                                       const float* __restrict__ weight,
                                       float* __restrict__ out,
                                       const int* __restrict__ flag_p, int D) {
    const int row = blockIdx.x;
    const int t = threadIdx.x;
    const int flag = *flag_p;
    const size_t base = (size_t)row * (size_t)D;

    float s = 0.f;
    for (int d = t; d < D; d += blockDim.x) {
        float xv = x[base + d];
        bool m;
        if (flag == 0)
            m = ((const unsigned char*)mask)[base + d] != 0;
        else if (flag == 1)
            m = ((const int*)mask)[base + d] != 0;
        else
            m = ((const float*)mask)[base + d] != 0.f;
        float xm = m ? xv : 0.f;
        s += xm * xm;
    }
#pragma unroll
    for (int off = 32; off > 0; off >>= 1) s += __shfl_down(s, off);
    __shared__ float ws[16];
    const int lane = t & 63;
    const int wave = t >> 6;
    if (lane == 0) ws[wave] = s;
    __syncthreads();
    float total = 0.f;
    const int nw = (blockDim.x + 63) / 64;
    for (int i = 0; i < nw; ++i) total += ws[i];
    const float scale = rsqrtf(total / (float)D + EPS_RMS);

    for (int d = t; d < D; d += blockDim.x) {
        float xv = x[base + d];
        bool m;
        if (flag == 0)
            m = ((const unsigned char*)mask)[base + d] != 0;
        else if (flag == 1)
            m = ((const int*)mask)[base + d] != 0;
        else
            m = ((const float*)mask)[base + d] != 0.f;
        float xm = m ? xv : 0.f;
        out[base + d] = weight[d] * xm * scale;
    }
}

extern "C" void kernel_launch(void* const* d_in, const int* in_sizes, int n_in,
                              void* d_out, int out_size, void* d_ws,
                              size_t ws_size, hipStream_t stream) {
    const float* x = (const float*)d_in[0];
    const void* mask = d_in[1];
    const float* weight = (const float*)d_in[2];
    float* out = (float*)d_out;

    const int D = in_sizes[2];         // weight length
    const int rows = in_sizes[0] / D;  // B*S

    int* flag = (int*)d_ws;
    detect_mask_kernel<<<1, 256, 0, stream>>>((const unsigned char*)mask, flag);

    if (D == 4096) {
        const int blocks = (rows + 3) / 4;  // 4 waves = 4 rows per block
        rmsnorm_sparse_wave4096<<<blocks, 256, 0, stream>>>(x, mask, weight,
                                                            out, flag, rows);
    } else {
        rmsnorm_sparse_generic<<<rows, 256, 0, stream>>>(x, mask, weight, out,
                                                         flag, D);
    }
}